// Round 1
// baseline (592.607 us; speedup 1.0000x reference)
//
#include <hip/hip_runtime.h>

#define TT 512
#define NB 512   // batch
#define II 32
#define HH 64

__device__ __forceinline__ float fexp2f(float x){ return __builtin_amdgcn_exp2f(x); }
__device__ __forceinline__ float frcpf(float x){ return __builtin_amdgcn_rcpf(x); }
// sigmoid(x) = 1/(1+e^-x) ; tanh(x) = 1 - 2/(1+e^{2x})
__device__ __forceinline__ float sigf(float x){ return frcpf(1.0f + fexp2f(-1.442695040888963f*x)); }
__device__ __forceinline__ float tanhf_fast(float x){ return 1.0f - 2.0f*frcpf(1.0f + fexp2f(2.885390081777926f*x)); }

// butterfly sum across the 4 lanes of a quad (ks dimension) via DPP quad_perm
__device__ __forceinline__ float quad_sum(float x){
  int xi = __builtin_bit_cast(int, x);
  int y  = __builtin_amdgcn_update_dpp(0, xi, 0xB1, 0xF, 0xF, true); // quad_perm [1,0,3,2]
  x += __builtin_bit_cast(float, y);
  xi = __builtin_bit_cast(int, x);
  y  = __builtin_amdgcn_update_dpp(0, xi, 0x4E, 0xF, 0xF, true);     // quad_perm [2,3,0,1]
  x += __builtin_bit_cast(float, y);
  return x;
}

__global__ __launch_bounds__(512, 2) void gru2_fused(
    const float* __restrict__ x,
    const float* __restrict__ Wih0, const float* __restrict__ Whh0,
    const float* __restrict__ bih0, const float* __restrict__ bhh0,
    const float* __restrict__ Wih1, const float* __restrict__ Whh1,
    const float* __restrict__ bih1, const float* __restrict__ bhh1,
    const float* __restrict__ fcw, const float* __restrict__ fcb,
    float* __restrict__ out)
{
  const int tid = threadIdx.x;
  const int b2  = tid >> 8;        // 0..1  : which batch of this block
  const int j   = (tid >> 2) & 63; // 0..63 : hidden unit owned
  const int ks  = tid & 3;         // 0..3  : k-slice
  const int b   = blockIdx.x * 2 + b2;

  __shared__ float h0buf[2][2][64]; // [b2][pingpong][h]
  __shared__ float h1buf[2][2][64];
  __shared__ float red[2][64];

  // zero initial states (both pingpong buffers)
  for (int i = tid; i < 256; i += 512) {
    (&h0buf[0][0][0])[i] = 0.0f;
    (&h1buf[0][0][0])[i] = 0.0f;
  }

  // ---- persistent per-thread weights (k-slice ks of gate rows j, 64+j, 128+j) ----
  float wih0[3][8], whh0[3][16], wih1[3][16], whh1[3][16];
#pragma unroll
  for (int g = 0; g < 3; ++g) {
    const int row = g*64 + j;
    {
      const float4* p = (const float4*)(Wih0 + row*II + ks*8);
      float4 a = p[0], q = p[1];
      wih0[g][0]=a.x; wih0[g][1]=a.y; wih0[g][2]=a.z; wih0[g][3]=a.w;
      wih0[g][4]=q.x; wih0[g][5]=q.y; wih0[g][6]=q.z; wih0[g][7]=q.w;
    }
    {
      const float4* p = (const float4*)(Whh0 + row*HH + ks*16);
#pragma unroll
      for (int c = 0; c < 4; ++c) {
        float4 a = p[c];
        whh0[g][c*4+0]=a.x; whh0[g][c*4+1]=a.y; whh0[g][c*4+2]=a.z; whh0[g][c*4+3]=a.w;
      }
    }
    {
      const float4* p = (const float4*)(Wih1 + row*HH + ks*16);
#pragma unroll
      for (int c = 0; c < 4; ++c) {
        float4 a = p[c];
        wih1[g][c*4+0]=a.x; wih1[g][c*4+1]=a.y; wih1[g][c*4+2]=a.z; wih1[g][c*4+3]=a.w;
      }
    }
    {
      const float4* p = (const float4*)(Whh1 + row*HH + ks*16);
#pragma unroll
      for (int c = 0; c < 4; ++c) {
        float4 a = p[c];
        whh1[g][c*4+0]=a.x; whh1[g][c*4+1]=a.y; whh1[g][c*4+2]=a.z; whh1[g][c*4+3]=a.w;
      }
    }
  }

  const float br0  = bih0[j]      + bhh0[j];
  const float bz0  = bih0[64+j]   + bhh0[64+j];
  const float bin0 = bih0[128+j];
  const float bhn0 = bhh0[128+j];
  const float br1  = bih1[j]      + bhh1[j];
  const float bz1  = bih1[64+j]   + bhh1[64+j];
  const float bin1 = bih1[128+j];
  const float bhn1 = bhh1[128+j];

  const float* xb = x + (size_t)b * (TT*II);
  float xc[8];
  {
    const float4* p = (const float4*)(xb + ks*8);
    float4 a = p[0], q = p[1];
    xc[0]=a.x; xc[1]=a.y; xc[2]=a.z; xc[3]=a.w; xc[4]=q.x; xc[5]=q.y; xc[6]=q.z; xc[7]=q.w;
  }

  int p0 = 0, p1 = 0;
  __syncthreads();

  for (int t = 0; t < TT; ++t) {
    // prefetch next timestep's x slice (used next iteration; latency hidden)
    const int tn = (t+1 < TT) ? (t+1) : t;
    const float4* px = (const float4*)(xb + tn*II + ks*8);
    const float4 xa4 = px[0], xb4 = px[1];

    // ================= layer 0 =================
    float hs[16];
#pragma unroll
    for (int c = 0; c < 4; ++c) {
      float4 v = *(const float4*)&h0buf[b2][p0][ks*16 + c*4];
      hs[c*4+0]=v.x; hs[c*4+1]=v.y; hs[c*4+2]=v.z; hs[c*4+3]=v.w;
    }
    float pr=0.f, pz=0.f, pni=0.f, pnh=0.f;
#pragma unroll
    for (int i = 0; i < 8; ++i) {
      pr  = fmaf(wih0[0][i], xc[i], pr);
      pz  = fmaf(wih0[1][i], xc[i], pz);
      pni = fmaf(wih0[2][i], xc[i], pni);
    }
#pragma unroll
    for (int k = 0; k < 16; ++k) {
      pr  = fmaf(whh0[0][k], hs[k], pr);
      pz  = fmaf(whh0[1][k], hs[k], pz);
      pnh = fmaf(whh0[2][k], hs[k], pnh);
    }
    pr = quad_sum(pr); pz = quad_sum(pz); pni = quad_sum(pni); pnh = quad_sum(pnh);
    {
      const float r  = sigf(pr + br0);
      const float z  = sigf(pz + bz0);
      const float n  = tanhf_fast(pni + bin0 + r*(pnh + bhn0));
      const float hp = h0buf[b2][p0][j];
      const float hn = n + z*(hp - n);   // (1-z)*n + z*hp
      if (ks == 0) h0buf[b2][p0^1][j] = hn;
    }
    __syncthreads();

    // ================= layer 1 =================
    float as_[16], bs_[16];
#pragma unroll
    for (int c = 0; c < 4; ++c) {
      float4 v = *(const float4*)&h0buf[b2][p0^1][ks*16 + c*4];
      as_[c*4+0]=v.x; as_[c*4+1]=v.y; as_[c*4+2]=v.z; as_[c*4+3]=v.w;
      float4 w = *(const float4*)&h1buf[b2][p1][ks*16 + c*4];
      bs_[c*4+0]=w.x; bs_[c*4+1]=w.y; bs_[c*4+2]=w.z; bs_[c*4+3]=w.w;
    }
    pr=0.f; pz=0.f; pni=0.f; pnh=0.f;
#pragma unroll
    for (int k = 0; k < 16; ++k) {
      pr  = fmaf(wih1[0][k], as_[k], pr);
      pz  = fmaf(wih1[1][k], as_[k], pz);
      pni = fmaf(wih1[2][k], as_[k], pni);
    }
#pragma unroll
    for (int k = 0; k < 16; ++k) {
      pr  = fmaf(whh1[0][k], bs_[k], pr);
      pz  = fmaf(whh1[1][k], bs_[k], pz);
      pnh = fmaf(whh1[2][k], bs_[k], pnh);
    }
    pr = quad_sum(pr); pz = quad_sum(pz); pni = quad_sum(pni); pnh = quad_sum(pnh);
    {
      const float r  = sigf(pr + br1);
      const float z  = sigf(pz + bz1);
      const float n  = tanhf_fast(pni + bin1 + r*(pnh + bhn1));
      const float hp = h1buf[b2][p1][j];
      const float hn = n + z*(hp - n);
      if (ks == 0) h1buf[b2][p1^1][j] = hn;
    }
    __syncthreads();

    p0 ^= 1; p1 ^= 1;
    xc[0]=xa4.x; xc[1]=xa4.y; xc[2]=xa4.z; xc[3]=xa4.w;
    xc[4]=xb4.x; xc[5]=xb4.y; xc[6]=xb4.z; xc[7]=xb4.w;
  }

  // ================= FC epilogue =================
  if (tid < 128) {
    const int bb = tid >> 6, jf = tid & 63;
    red[bb][jf] = h1buf[bb][p1][jf] * fcw[jf];
  }
  __syncthreads();
  if (tid < 2) {
    float s = fcb[0];
#pragma unroll
    for (int i = 0; i < 64; ++i) s += red[tid][i];
    out[blockIdx.x*2 + tid] = s;
  }
}

extern "C" void kernel_launch(void* const* d_in, const int* in_sizes, int n_in,
                              void* d_out, int out_size, void* d_ws, size_t ws_size,
                              hipStream_t stream) {
  const float* x    = (const float*)d_in[0];
  const float* Wih0 = (const float*)d_in[1];
  const float* Whh0 = (const float*)d_in[2];
  const float* bih0 = (const float*)d_in[3];
  const float* bhh0 = (const float*)d_in[4];
  const float* Wih1 = (const float*)d_in[5];
  const float* Whh1 = (const float*)d_in[6];
  const float* bih1 = (const float*)d_in[7];
  const float* bhh1 = (const float*)d_in[8];
  const float* fcw  = (const float*)d_in[9];
  const float* fcb  = (const float*)d_in[10];
  float* out = (float*)d_out;

  gru2_fused<<<dim3(NB/2), dim3(512), 0, stream>>>(
      x, Wih0, Whh0, bih0, bhh0, Wih1, Whh1, bih1, bhh1, fcw, fcb, out);
}

// Round 2
// 481.093 us; speedup vs baseline: 1.2318x; 1.2318x over previous
//
#include <hip/hip_runtime.h>

#define TT 512
#define NB 512
#define II 32
#define HH 64

static __device__ __forceinline__ float fexp2f(float x){ return __builtin_amdgcn_exp2f(x); }
static __device__ __forceinline__ float frcpf(float x){ return __builtin_amdgcn_rcpf(x); }
static __device__ __forceinline__ float sigf(float x){ return frcpf(1.0f + fexp2f(-1.442695040888963f*x)); }
static __device__ __forceinline__ float tanhf_fast(float x){ return 1.0f - 2.0f*frcpf(1.0f + fexp2f(2.885390081777926f*x)); }

// butterfly sum across the 4 lanes of a quad (ks dimension) via DPP quad_perm
static __device__ __forceinline__ float quad_sum(float x){
  int xi = __builtin_bit_cast(int, x);
  int y  = __builtin_amdgcn_update_dpp(0, xi, 0xB1, 0xF, 0xF, true); // quad_perm [1,0,3,2]
  x += __builtin_bit_cast(float, y);
  xi = __builtin_bit_cast(int, x);
  y  = __builtin_amdgcn_update_dpp(0, xi, 0x4E, 0xF, 0xF, true);     // quad_perm [2,3,0,1]
  x += __builtin_bit_cast(float, y);
  return x;
}

// 256 threads = 1 batch = 4 waves. grid 512 -> 2 blocks/CU (independent
// barrier domains). waves_per_eu(2,2) pins allocator to 256 VGPRs so all
// 168 weight floats stay resident (R1: compiler chose 116 and re-loaded).
__global__ __attribute__((amdgpu_flat_work_group_size(256,256)))
__attribute__((amdgpu_waves_per_eu(2,2)))
void gru2_fused(
    const float* __restrict__ x,
    const float* __restrict__ Wih0, const float* __restrict__ Whh0,
    const float* __restrict__ bih0, const float* __restrict__ bhh0,
    const float* __restrict__ Wih1, const float* __restrict__ Whh1,
    const float* __restrict__ bih1, const float* __restrict__ bhh1,
    const float* __restrict__ fcw, const float* __restrict__ fcb,
    float* __restrict__ out)
{
  const int tid = threadIdx.x;
  const int j   = tid >> 2;   // 0..63 hidden unit owned
  const int ks  = tid & 3;    // 0..3 k-slice
  const int b   = blockIdx.x;

  __shared__ float h0buf[2][64]; // pingpong
  __shared__ float h1buf[2][64];

  // ---- persistent per-thread weights (k-slice ks of gate rows j, 64+j, 128+j) ----
  float wih0[3][8], whh0[3][16], wih1[3][16], whh1[3][16];
#pragma unroll
  for (int g = 0; g < 3; ++g) {
    const int row = g*64 + j;
    {
      const float4* p = (const float4*)(Wih0 + row*II + ks*8);
      float4 a = p[0], q = p[1];
      wih0[g][0]=a.x; wih0[g][1]=a.y; wih0[g][2]=a.z; wih0[g][3]=a.w;
      wih0[g][4]=q.x; wih0[g][5]=q.y; wih0[g][6]=q.z; wih0[g][7]=q.w;
    }
    {
      const float4* p = (const float4*)(Whh0 + row*HH + ks*16);
#pragma unroll
      for (int c = 0; c < 4; ++c) {
        float4 a = p[c];
        whh0[g][c*4+0]=a.x; whh0[g][c*4+1]=a.y; whh0[g][c*4+2]=a.z; whh0[g][c*4+3]=a.w;
      }
    }
    {
      const float4* p = (const float4*)(Wih1 + row*HH + ks*16);
#pragma unroll
      for (int c = 0; c < 4; ++c) {
        float4 a = p[c];
        wih1[g][c*4+0]=a.x; wih1[g][c*4+1]=a.y; wih1[g][c*4+2]=a.z; wih1[g][c*4+3]=a.w;
      }
    }
    {
      const float4* p = (const float4*)(Whh1 + row*HH + ks*16);
#pragma unroll
      for (int c = 0; c < 4; ++c) {
        float4 a = p[c];
        whh1[g][c*4+0]=a.x; whh1[g][c*4+1]=a.y; whh1[g][c*4+2]=a.z; whh1[g][c*4+3]=a.w;
      }
    }
  }

  const float br0  = bih0[j]      + bhh0[j];
  const float bz0  = bih0[64+j]   + bhh0[64+j];
  const float bin0 = bih0[128+j];
  const float bhn0 = bhh0[128+j];
  const float br1  = bih1[j]      + bhh1[j];
  const float bz1  = bih1[64+j]   + bhh1[64+j];
  const float bin1 = bih1[128+j];
  const float bhn1 = bhh1[128+j];

  const float* xb = x + (size_t)b * (TT*II);

  // xc = x[0]
  float xc[8];
  {
    const float4* p = (const float4*)(xb + ks*8);
    float4 a = p[0], q = p[1];
    xc[0]=a.x; xc[1]=a.y; xc[2]=a.z; xc[3]=a.w; xc[4]=q.x; xc[5]=q.y; xc[6]=q.z; xc[7]=q.w;
  }

  // h1[-1] = 0
  if (tid < 64) h1buf[0][tid] = 0.0f;

  // ---- prologue: layer0 step t=0 with h_prev = 0 ----
  float hp0, hp1 = 0.0f; // h_prev carried in registers (all ks lanes hold it)
  {
    float pr=0.f, pz=0.f, pni=0.f;
#pragma unroll
    for (int i = 0; i < 8; ++i) {
      pr  = fmaf(wih0[0][i], xc[i], pr);
      pz  = fmaf(wih0[1][i], xc[i], pz);
      pni = fmaf(wih0[2][i], xc[i], pni);
    }
    pr = quad_sum(pr); pz = quad_sum(pz); pni = quad_sum(pni);
    const float r = sigf(pr + br0);
    const float z = sigf(pz + bz0);
    const float n = tanhf_fast(pni + bin0 + r*bhn0);
    hp0 = n - z*n;                  // h0out[0]
    if (ks == 0) h0buf[0][j] = hp0;
  }
  // xc = x[1]
  {
    const float4* p = (const float4*)(xb + II + ks*8);
    float4 a = p[0], q = p[1];
    xc[0]=a.x; xc[1]=a.y; xc[2]=a.z; xc[3]=a.w; xc[4]=q.x; xc[5]=q.y; xc[6]=q.z; xc[7]=q.w;
  }
  __syncthreads();

  // ---- main: phase p computes layer0 step p+1 AND layer1 step p ----
  for (int p = 0; p < TT-1; ++p) {
    const int cur = p & 1, nxt = cur ^ 1;

    // prefetch x[p+2] (consumed next phase; full phase to cover latency)
    const int tn = (p+2 < TT) ? (p+2) : (TT-1);
    const float4* px = (const float4*)(xb + tn*II + ks*8);
    const float4 xa4 = px[0], xb4 = px[1];

    // hs = h0out[p] slice (shared: layer0 h_prev AND layer1 input)
    // bs = h1[p-1] slice
    float hs[16], bs[16];
#pragma unroll
    for (int c = 0; c < 4; ++c) {
      float4 v = *(const float4*)&h0buf[cur][ks*16 + c*4];
      hs[c*4+0]=v.x; hs[c*4+1]=v.y; hs[c*4+2]=v.z; hs[c*4+3]=v.w;
      float4 w = *(const float4*)&h1buf[cur][ks*16 + c*4];
      bs[c*4+0]=w.x; bs[c*4+1]=w.y; bs[c*4+2]=w.z; bs[c*4+3]=w.w;
    }

    float pr0=0.f, pz0=0.f, pni0=0.f, pnh0=0.f;
    float pr1=0.f, pz1=0.f, pni1=0.f, pnh1=0.f;
#pragma unroll
    for (int i = 0; i < 8; ++i) {
      pr0  = fmaf(wih0[0][i], xc[i], pr0);
      pz0  = fmaf(wih0[1][i], xc[i], pz0);
      pni0 = fmaf(wih0[2][i], xc[i], pni0);
    }
#pragma unroll
    for (int k = 0; k < 16; ++k) {
      pr0  = fmaf(whh0[0][k], hs[k], pr0);
      pz0  = fmaf(whh0[1][k], hs[k], pz0);
      pnh0 = fmaf(whh0[2][k], hs[k], pnh0);
      pr1  = fmaf(wih1[0][k], hs[k], pr1);
      pz1  = fmaf(wih1[1][k], hs[k], pz1);
      pni1 = fmaf(wih1[2][k], hs[k], pni1);
      pr1  = fmaf(whh1[0][k], bs[k], pr1);
      pz1  = fmaf(whh1[1][k], bs[k], pz1);
      pnh1 = fmaf(whh1[2][k], bs[k], pnh1);
    }
    pr0 = quad_sum(pr0); pz0 = quad_sum(pz0); pni0 = quad_sum(pni0); pnh0 = quad_sum(pnh0);
    pr1 = quad_sum(pr1); pz1 = quad_sum(pz1); pni1 = quad_sum(pni1); pnh1 = quad_sum(pnh1);

    // layer0 step p+1
    {
      const float r = sigf(pr0 + br0);
      const float z = sigf(pz0 + bz0);
      const float n = tanhf_fast(pni0 + bin0 + r*(pnh0 + bhn0));
      hp0 = n + z*(hp0 - n);
      if (ks == 0) h0buf[nxt][j] = hp0;
    }
    // layer1 step p
    {
      const float r = sigf(pr1 + br1);
      const float z = sigf(pz1 + bz1);
      const float n = tanhf_fast(pni1 + bin1 + r*(pnh1 + bhn1));
      hp1 = n + z*(hp1 - n);
      if (ks == 1) h1buf[nxt][j] = hp1;
    }
    __syncthreads();

    xc[0]=xa4.x; xc[1]=xa4.y; xc[2]=xa4.z; xc[3]=xa4.w;
    xc[4]=xb4.x; xc[5]=xb4.y; xc[6]=xb4.z; xc[7]=xb4.w;
  }

  // ---- epilogue phase p=511: layer1 only ----
  {
    const int cur = (TT-1) & 1; // = 1
    float hs[16], bs[16];
#pragma unroll
    for (int c = 0; c < 4; ++c) {
      float4 v = *(const float4*)&h0buf[cur][ks*16 + c*4];
      hs[c*4+0]=v.x; hs[c*4+1]=v.y; hs[c*4+2]=v.z; hs[c*4+3]=v.w;
      float4 w = *(const float4*)&h1buf[cur][ks*16 + c*4];
      bs[c*4+0]=w.x; bs[c*4+1]=w.y; bs[c*4+2]=w.z; bs[c*4+3]=w.w;
    }
    float pr1=0.f, pz1=0.f, pni1=0.f, pnh1=0.f;
#pragma unroll
    for (int k = 0; k < 16; ++k) {
      pr1  = fmaf(wih1[0][k], hs[k], pr1);
      pz1  = fmaf(wih1[1][k], hs[k], pz1);
      pni1 = fmaf(wih1[2][k], hs[k], pni1);
      pr1  = fmaf(whh1[0][k], bs[k], pr1);
      pz1  = fmaf(whh1[1][k], bs[k], pz1);
      pnh1 = fmaf(whh1[2][k], bs[k], pnh1);
    }
    pr1 = quad_sum(pr1); pz1 = quad_sum(pz1); pni1 = quad_sum(pni1); pnh1 = quad_sum(pnh1);
    const float r = sigf(pr1 + br1);
    const float z = sigf(pz1 + bz1);
    const float n = tanhf_fast(pni1 + bin1 + r*(pnh1 + bhn1));
    hp1 = n + z*(hp1 - n);          // h1[511]
  }

  // ---- FC epilogue: out[b] = fcb + sum_j h1[511][j]*fcw[j] ----
  __syncthreads();                   // reuse h1buf[0]
  if (ks == 0) h1buf[0][j] = hp1;
  __syncthreads();
  if (tid < 64) {
    float v = h1buf[0][tid] * fcw[tid];
#pragma unroll
    for (int off = 32; off >= 1; off >>= 1)
      v += __shfl_xor(v, off, 64);
    if (tid == 0) out[b] = v + fcb[0];
  }
}

extern "C" void kernel_launch(void* const* d_in, const int* in_sizes, int n_in,
                              void* d_out, int out_size, void* d_ws, size_t ws_size,
                              hipStream_t stream) {
  const float* x    = (const float*)d_in[0];
  const float* Wih0 = (const float*)d_in[1];
  const float* Whh0 = (const float*)d_in[2];
  const float* bih0 = (const float*)d_in[3];
  const float* bhh0 = (const float*)d_in[4];
  const float* Wih1 = (const float*)d_in[5];
  const float* Whh1 = (const float*)d_in[6];
  const float* bih1 = (const float*)d_in[7];
  const float* bhh1 = (const float*)d_in[8];
  const float* fcw  = (const float*)d_in[9];
  const float* fcb  = (const float*)d_in[10];
  float* out = (float*)d_out;

  gru2_fused<<<dim3(NB), dim3(256), 0, stream>>>(
      x, Wih0, Whh0, bih0, bhh0, Wih1, Whh1, bih1, bhh1, fcw, fcb, out);
}

// Round 3
// 388.246 us; speedup vs baseline: 1.5264x; 1.2391x over previous
//
#include <hip/hip_runtime.h>

typedef float v2f __attribute__((ext_vector_type(2)));

#define TT 512
#define NB 512
#define II 32
#define HH 64

static __device__ __forceinline__ float fexp2f(float x){ return __builtin_amdgcn_exp2f(x); }
static __device__ __forceinline__ float frcpf(float x){ return __builtin_amdgcn_rcpf(x); }
static __device__ __forceinline__ float sigf(float x){ return frcpf(1.0f + fexp2f(-1.442695040888963f*x)); }
static __device__ __forceinline__ float tanhf_fast(float x){ return 1.0f - 2.0f*frcpf(1.0f + fexp2f(2.885390081777926f*x)); }

static __device__ __forceinline__ v2f pfma(v2f a, v2f b, v2f c){ return __builtin_elementwise_fma(a, b, c); }
static __device__ __forceinline__ v2f mk2(float a, float b){ v2f r; r.x = a; r.y = b; return r; }

// butterfly sum across the 4 lanes of a quad (ks dimension) via DPP quad_perm
static __device__ __forceinline__ float quad_sum(float x){
  int xi = __builtin_bit_cast(int, x);
  int y  = __builtin_amdgcn_update_dpp(0, xi, 0xB1, 0xF, 0xF, true); // quad_perm [1,0,3,2]
  x += __builtin_bit_cast(float, y);
  xi = __builtin_bit_cast(int, x);
  y  = __builtin_amdgcn_update_dpp(0, xi, 0x4E, 0xF, 0xF, true);     // quad_perm [2,3,0,1]
  x += __builtin_bit_cast(float, y);
  return x;
}

// load 8 consecutive floats as 4 v2f
static __device__ __forceinline__ void ld8(const float* p, v2f* dst){
  float4 a = ((const float4*)p)[0], b = ((const float4*)p)[1];
  dst[0] = mk2(a.x, a.y); dst[1] = mk2(a.z, a.w);
  dst[2] = mk2(b.x, b.y); dst[3] = mk2(b.z, b.w);
}

// 256 threads = 1 batch = 4 waves; grid 512 -> 2 blocks/CU (two independent
// barrier domains). waves_per_eu(2,2) -> 256-VGPR budget; asm pins below
// force the 168 weight floats to actually STAY resident (R2: compiler
// rematerialized the weight loads each phase and allocated only 128).
__global__ __attribute__((amdgpu_flat_work_group_size(256,256)))
__attribute__((amdgpu_waves_per_eu(2,2)))
void gru2_fused(
    const float* __restrict__ x,
    const float* __restrict__ Wih0, const float* __restrict__ Whh0,
    const float* __restrict__ bih0, const float* __restrict__ bhh0,
    const float* __restrict__ Wih1, const float* __restrict__ Whh1,
    const float* __restrict__ b_ih1, const float* __restrict__ b_hh1,
    const float* __restrict__ fcw, const float* __restrict__ fcb,
    float* __restrict__ out)
{
  const int tid = threadIdx.x;
  const int j   = tid >> 2;   // 0..63 hidden unit owned
  const int ks  = tid & 3;    // 0..3 k-slice
  const int b   = blockIdx.x;

  __shared__ float h0buf[2][64]; // pingpong
  __shared__ float h1buf[2][64];

  // ---- persistent per-thread weights (k-slice ks of gate rows j, 64+j, 128+j) ----
  v2f wih0[3][4], whh0[3][8], wih1[3][8], whh1[3][8];
#pragma unroll
  for (int g = 0; g < 3; ++g) {
    const int row = g*64 + j;
    ld8(Wih0 + row*II + ks*8,      wih0[g]);
    ld8(Whh0 + row*HH + ks*16,     whh0[g]);
    ld8(Whh0 + row*HH + ks*16 + 8, whh0[g] + 4);
    ld8(Wih1 + row*HH + ks*16,     wih1[g]);
    ld8(Wih1 + row*HH + ks*16 + 8, wih1[g] + 4);
    ld8(Whh1 + row*HH + ks*16,     whh1[g]);
    ld8(Whh1 + row*HH + ks*16 + 8, whh1[g] + 4);
  }
  // pin: value is no longer a pure load result -> allocator cannot
  // rematerialize-from-global; must keep in VGPRs (budget 256).
#pragma unroll
  for (int g = 0; g < 3; ++g) {
#pragma unroll
    for (int i = 0; i < 4; ++i) asm volatile("" : "+v"(wih0[g][i]));
#pragma unroll
    for (int i = 0; i < 8; ++i) {
      asm volatile("" : "+v"(whh0[g][i]));
      asm volatile("" : "+v"(wih1[g][i]));
      asm volatile("" : "+v"(whh1[g][i]));
    }
  }

  const float br0  = bih0[j]      + bhh0[j];
  const float bz0  = bih0[64+j]   + bhh0[64+j];
  const float bin0 = bih0[128+j];
  const float bhn0 = bhh0[128+j];
  const float br1  = b_ih1[j]     + b_hh1[j];
  const float bz1  = b_ih1[64+j]  + b_hh1[64+j];
  const float bin1 = b_ih1[128+j];
  const float bhn1 = b_hh1[128+j];

  const float* xb = x + (size_t)b * (TT*II);

  // xc = x[0]
  v2f xc[4];
  ld8(xb + ks*8, xc);

  // h1[-1] = 0
  if (tid < 64) h1buf[0][tid] = 0.0f;

  // ---- prologue: layer0 step t=0 with h_prev = 0 ----
  float hp0, hp1 = 0.0f; // h_prev carried in registers (all ks lanes hold it)
  {
    v2f ar = {0.f,0.f}, az = {0.f,0.f}, an = {0.f,0.f};
#pragma unroll
    for (int i = 0; i < 4; ++i) {
      ar = pfma(wih0[0][i], xc[i], ar);
      az = pfma(wih0[1][i], xc[i], az);
      an = pfma(wih0[2][i], xc[i], an);
    }
    const float pr  = quad_sum(ar.x + ar.y);
    const float pz  = quad_sum(az.x + az.y);
    const float pni = quad_sum(an.x + an.y);
    const float r = sigf(pr + br0);
    const float z = sigf(pz + bz0);
    const float n = tanhf_fast(pni + bin0 + r*bhn0);
    hp0 = n - z*n;                  // h0out[0]
    if (ks == 0) h0buf[0][j] = hp0;
  }
  // xc = x[1]
  ld8(xb + II + ks*8, xc);
  __syncthreads();

  // ---- main: phase p computes layer0 step p+1 AND layer1 step p ----
  for (int p = 0; p < TT-1; ++p) {
    const int cur = p & 1, nxt = cur ^ 1;

    // hs = h0out[p] slice (shared: layer0 h_prev AND layer1 input)
    // bs = h1[p-1] slice
    v2f hs[8], bs[8];
#pragma unroll
    for (int c = 0; c < 4; ++c) {
      float4 v = *(const float4*)&h0buf[cur][ks*16 + c*4];
      hs[2*c+0] = mk2(v.x, v.y); hs[2*c+1] = mk2(v.z, v.w);
      float4 w = *(const float4*)&h1buf[cur][ks*16 + c*4];
      bs[2*c+0] = mk2(w.x, w.y); bs[2*c+1] = mk2(w.z, w.w);
    }

    v2f ar0 = {0.f,0.f}, az0 = {0.f,0.f}, ani0 = {0.f,0.f}, anh0 = {0.f,0.f};
    v2f ar1 = {0.f,0.f}, az1 = {0.f,0.f}, ani1 = {0.f,0.f}, anh1 = {0.f,0.f};
#pragma unroll
    for (int i = 0; i < 4; ++i) {
      ar0  = pfma(wih0[0][i], xc[i], ar0);
      az0  = pfma(wih0[1][i], xc[i], az0);
      ani0 = pfma(wih0[2][i], xc[i], ani0);
    }
    // reload xc in place for next phase (x[p+2]); last use was just above.
    // Remaining ~300 cyc of this phase covers the load latency.
    {
      const int tn = (p+2 < TT) ? (p+2) : (TT-1);
      ld8(xb + tn*II + ks*8, xc);
    }
#pragma unroll
    for (int k = 0; k < 8; ++k) {
      ar0  = pfma(whh0[0][k], hs[k], ar0);
      az0  = pfma(whh0[1][k], hs[k], az0);
      anh0 = pfma(whh0[2][k], hs[k], anh0);
      ar1  = pfma(wih1[0][k], hs[k], ar1);
      az1  = pfma(wih1[1][k], hs[k], az1);
      ani1 = pfma(wih1[2][k], hs[k], ani1);
      ar1  = pfma(whh1[0][k], bs[k], ar1);
      az1  = pfma(whh1[1][k], bs[k], az1);
      anh1 = pfma(whh1[2][k], bs[k], anh1);
    }
    const float pr0  = quad_sum(ar0.x  + ar0.y);
    const float pz0  = quad_sum(az0.x  + az0.y);
    const float pni0 = quad_sum(ani0.x + ani0.y);
    const float pnh0 = quad_sum(anh0.x + anh0.y);
    const float pr1  = quad_sum(ar1.x  + ar1.y);
    const float pz1  = quad_sum(az1.x  + az1.y);
    const float pni1 = quad_sum(ani1.x + ani1.y);
    const float pnh1 = quad_sum(anh1.x + anh1.y);

    // layer0 step p+1
    {
      const float r = sigf(pr0 + br0);
      const float z = sigf(pz0 + bz0);
      const float n = tanhf_fast(pni0 + bin0 + r*(pnh0 + bhn0));
      hp0 = n + z*(hp0 - n);
      if (ks == 0) h0buf[nxt][j] = hp0;
    }
    // layer1 step p
    {
      const float r = sigf(pr1 + br1);
      const float z = sigf(pz1 + bz1);
      const float n = tanhf_fast(pni1 + bin1 + r*(pnh1 + bhn1));
      hp1 = n + z*(hp1 - n);
      if (ks == 1) h1buf[nxt][j] = hp1;
    }
    __syncthreads();
  }

  // ---- epilogue phase p=511: layer1 only ----
  {
    const int cur = (TT-1) & 1; // = 1
    v2f hs[8], bs[8];
#pragma unroll
    for (int c = 0; c < 4; ++c) {
      float4 v = *(const float4*)&h0buf[cur][ks*16 + c*4];
      hs[2*c+0] = mk2(v.x, v.y); hs[2*c+1] = mk2(v.z, v.w);
      float4 w = *(const float4*)&h1buf[cur][ks*16 + c*4];
      bs[2*c+0] = mk2(w.x, w.y); bs[2*c+1] = mk2(w.z, w.w);
    }
    v2f ar1 = {0.f,0.f}, az1 = {0.f,0.f}, ani1 = {0.f,0.f}, anh1 = {0.f,0.f};
#pragma unroll
    for (int k = 0; k < 8; ++k) {
      ar1  = pfma(wih1[0][k], hs[k], ar1);
      az1  = pfma(wih1[1][k], hs[k], az1);
      ani1 = pfma(wih1[2][k], hs[k], ani1);
      ar1  = pfma(whh1[0][k], bs[k], ar1);
      az1  = pfma(whh1[1][k], bs[k], az1);
      anh1 = pfma(whh1[2][k], bs[k], anh1);
    }
    const float pr1  = quad_sum(ar1.x  + ar1.y);
    const float pz1  = quad_sum(az1.x  + az1.y);
    const float pni1 = quad_sum(ani1.x + ani1.y);
    const float pnh1 = quad_sum(anh1.x + anh1.y);
    const float r = sigf(pr1 + br1);
    const float z = sigf(pz1 + bz1);
    const float n = tanhf_fast(pni1 + bin1 + r*(pnh1 + bhn1));
    hp1 = n + z*(hp1 - n);          // h1[511]
  }

  // ---- FC epilogue: out[b] = fcb + sum_j h1[511][j]*fcw[j] ----
  __syncthreads();                   // safe to reuse h1buf[0]
  if (ks == 0) h1buf[0][j] = hp1;
  __syncthreads();
  if (tid < 64) {
    float v = h1buf[0][tid] * fcw[tid];
#pragma unroll
    for (int off = 32; off >= 1; off >>= 1)
      v += __shfl_xor(v, off, 64);
    if (tid == 0) out[b] = v + fcb[0];
  }
}

extern "C" void kernel_launch(void* const* d_in, const int* in_sizes, int n_in,
                              void* d_out, int out_size, void* d_ws, size_t ws_size,
                              hipStream_t stream) {
  const float* x    = (const float*)d_in[0];
  const float* Wih0 = (const float*)d_in[1];
  const float* Whh0 = (const float*)d_in[2];
  const float* bih0 = (const float*)d_in[3];
  const float* bhh0 = (const float*)d_in[4];
  const float* Wih1 = (const float*)d_in[5];
  const float* Whh1 = (const float*)d_in[6];
  const float* bih1 = (const float*)d_in[7];
  const float* bhh1 = (const float*)d_in[8];
  const float* fcw  = (const float*)d_in[9];
  const float* fcb  = (const float*)d_in[10];
  float* out = (float*)d_out;

  gru2_fused<<<dim3(NB), dim3(256), 0, stream>>>(
      x, Wih0, Whh0, bih0, bhh0, Wih1, Whh1, bih1, bhh1, fcw, fcb, out);
}